// Round 5
// baseline (398.955 us; speedup 1.0000x reference)
//
#include <hip/hip_runtime.h>
#include <hip/hip_cooperative_groups.h>
#include <math.h>

namespace cg = cooperative_groups;

// ---------------------------------------------------------------------------
// Att_cov, round 5: ONE cooperative kernel, 3 grid.sync()s, zero global
// atomics. Phases:
//  A: per-node projections (pa,pb,h) + partitioned degree histogram
//  B: dinv (g=h*dinv) + edge sigmoid outputs
//  C: partitioned GCN scatter (table[col-lo] += g[row])
//  D: per-graph partial-reduce + two chained ragged softmaxes (graph-local)
// Histogram/scatter: nodes in R ranges of RANGE=4096 (16KB LDS), edges in C
// chunks, task (r,c) scans chunk c with XCD-affine mapping (c%8==blk%8) so
// each chunk stays in one XCD's L2; tables written with plain stores.
// ws (floats): ed2[2N] | hbuf[N] (h->g) | dv1[N] | accfb[N] | partial[C*N]
// ---------------------------------------------------------------------------

#define RANGE 4096
#define BD 256

__global__ __launch_bounds__(BD)
void k_fused(const float* __restrict__ x,
             const int* __restrict__ ei,
             const int* __restrict__ splitn,
             const float* __restrict__ W_edge,
             const float* __restrict__ b_edge,
             const float* __restrict__ W_gcn,
             float* __restrict__ edge_m, float* __restrict__ edge_s,
             float* __restrict__ node_m, float* __restrict__ node_s,
             float2* __restrict__ ed2,
             float* __restrict__ hbuf,
             float* __restrict__ dv1,
             float* __restrict__ accfb,
             float* __restrict__ partial,
             int N, int E, int G, int C, int R, int CH, int vec)
{
    __shared__ float table[RANGE];       // hist/scat table; softmax row buffer
    __shared__ float4 Wa[16], Wb[16], Wg[16];
    __shared__ float red[BD];
    __shared__ int ired[BD];
    __shared__ int sh_off;

    cg::grid_group gridg = cg::this_grid();
    const int b = blockIdx.x, tid = threadIdx.x;
    const int NB = gridDim.x;

    if (tid < 16) {
        Wa[tid] = ((const float4*)W_edge)[tid];
        Wb[tid] = ((const float4*)W_edge)[16 + tid];
        Wg[tid] = ((const float4*)W_gcn)[tid];
    }
    __syncthreads();

    // ---------------- Phase A1: node projections (16 lanes/node) ----------
    {
        const long long total = (long long)N * 16;
        const long long stride = (long long)NB * BD;
        for (long long idx = (long long)b * BD + tid; idx < total; idx += stride) {
            int i = (int)(idx >> 4);
            int lane = (int)(idx & 15);
            float4 v = ((const float4*)(x + (size_t)i * 64))[lane];
            float4 wa = Wa[lane], wb = Wb[lane], wg = Wg[lane];
            float p1 = v.x*wa.x + v.y*wa.y + v.z*wa.z + v.w*wa.w;
            float p2 = v.x*wb.x + v.y*wb.y + v.z*wb.z + v.w*wb.w;
            float p3 = v.x*wg.x + v.y*wg.y + v.z*wg.z + v.w*wg.w;
#pragma unroll
            for (int s = 1; s < 16; s <<= 1) {
                p1 += __shfl_xor(p1, s);
                p2 += __shfl_xor(p2, s);
                p3 += __shfl_xor(p3, s);
            }
            if (lane == 0) {
                ed2[i] = make_float2(p1, p2);
                hbuf[i] = p3;
            }
        }
    }

    // ---------------- Phase A2: degree histogram (XCD-affine tasks) -------
    {
        const int xcd = b & 7, q = b >> 3;
        const int NBX = NB >> 3;             // NB is a multiple of 8 (host)
        const int CX = C >> 3;               // C is a multiple of 8 (host)
        const int TX = CX * R;
        const int* __restrict__ col = ei + E;
        for (int lt = q; lt < TX; lt += NBX) {
            int ci = lt / R, r = lt - ci * R;
            int c = (ci << 3) | xcd;
            int lo = r * RANGE;
            for (int j = tid; j < RANGE; j += BD) table[j] = 0.f;
            __syncthreads();
            int e_lo = c * CH;
            int e_hi = (E < e_lo + CH) ? E : (e_lo + CH);
            for (int e = e_lo + tid * 4; e < e_hi; e += BD * 4) {
                if (vec && e + 3 < e_hi) {
                    int4 cc = *(const int4*)(col + e);
                    unsigned u;
                    u = (unsigned)(cc.x - lo); if (u < RANGE) atomicAdd(&table[u], 1.f);
                    u = (unsigned)(cc.y - lo); if (u < RANGE) atomicAdd(&table[u], 1.f);
                    u = (unsigned)(cc.z - lo); if (u < RANGE) atomicAdd(&table[u], 1.f);
                    u = (unsigned)(cc.w - lo); if (u < RANGE) atomicAdd(&table[u], 1.f);
                } else {
                    int ee = (e_hi < e + 4) ? e_hi : e + 4;
                    for (int qq = e; qq < ee; ++qq) {
                        unsigned u = (unsigned)(col[qq] - lo);
                        if (u < RANGE) atomicAdd(&table[u], 1.f);
                    }
                }
            }
            __syncthreads();
            size_t base = (size_t)c * N;
            for (int j = tid; j < RANGE; j += BD) {
                int node = lo + j;
                if (node < N) partial[base + node] = table[j];
            }
            __syncthreads();
        }
    }
    gridg.sync();   // SYNC 1

    // ---------------- Phase B1: dinv; g = h*dinv ---------------------------
    for (int i = b * BD + tid; i < N; i += NB * BD) {
        float deg = 1.f;                     // self-loop
        for (int c = 0; c < C; ++c) deg += partial[(size_t)c * N + i];
        float dv = rsqrtf(deg);
        hbuf[i] *= dv;                       // g = h * dinv
        dv1[i] = dv;
    }

    // ---------------- Phase B2: edge sigmoid -------------------------------
    {
        const float bb = b_edge[0];
        const long long stride4 = (long long)NB * BD * 4;
        for (long long e0 = ((long long)b * BD + tid) * 4; e0 < E; e0 += stride4) {
            if (vec && e0 + 3 < E) {
                int4 r = *(const int4*)(ei + e0);
                int4 c = *(const int4*)(ei + E + e0);
                float4 m;
                m.x = 1.f / (1.f + expf(-(ed2[r.x].x + ed2[c.x].y + bb)));
                m.y = 1.f / (1.f + expf(-(ed2[r.y].x + ed2[c.y].y + bb)));
                m.z = 1.f / (1.f + expf(-(ed2[r.z].x + ed2[c.z].y + bb)));
                m.w = 1.f / (1.f + expf(-(ed2[r.w].x + ed2[c.w].y + bb)));
                *(float4*)(edge_m + e0) = m;
                *(float4*)(edge_s + e0) = make_float4(1.f - m.x, 1.f - m.y,
                                                      1.f - m.z, 1.f - m.w);
            } else {
                long long ee = (E < e0 + 4) ? E : e0 + 4;
                for (long long e = e0; e < ee; ++e) {
                    float a = 1.f / (1.f + expf(-(ed2[ei[e]].x + ed2[ei[E + e]].y + bb)));
                    edge_m[e] = a; edge_s[e] = 1.f - a;
                }
            }
        }
    }
    gridg.sync();   // SYNC 2

    // ---------------- Phase C: GCN scatter (XCD-affine tasks) --------------
    {
        const int xcd = b & 7, q = b >> 3;
        const int NBX = NB >> 3;
        const int CX = C >> 3;
        const int TX = CX * R;
        const int* __restrict__ row = ei;
        const int* __restrict__ col = ei + E;
        for (int lt = q; lt < TX; lt += NBX) {
            int ci = lt / R, r = lt - ci * R;
            int c = (ci << 3) | xcd;
            int lo = r * RANGE;
            for (int j = tid; j < RANGE; j += BD) table[j] = 0.f;
            __syncthreads();
            int e_lo = c * CH;
            int e_hi = (E < e_lo + CH) ? E : (e_lo + CH);
            for (int e = e_lo + tid * 4; e < e_hi; e += BD * 4) {
                if (vec && e + 3 < e_hi) {
                    int4 rr = *(const int4*)(row + e);
                    int4 cc = *(const int4*)(col + e);
                    unsigned u;
                    u = (unsigned)(cc.x - lo); if (u < RANGE) atomicAdd(&table[u], hbuf[rr.x]);
                    u = (unsigned)(cc.y - lo); if (u < RANGE) atomicAdd(&table[u], hbuf[rr.y]);
                    u = (unsigned)(cc.z - lo); if (u < RANGE) atomicAdd(&table[u], hbuf[rr.z]);
                    u = (unsigned)(cc.w - lo); if (u < RANGE) atomicAdd(&table[u], hbuf[rr.w]);
                } else {
                    int ee = (e_hi < e + 4) ? e_hi : e + 4;
                    for (int qq = e; qq < ee; ++qq) {
                        unsigned u = (unsigned)(col[qq] - lo);
                        if (u < RANGE) atomicAdd(&table[u], hbuf[row[qq]]);
                    }
                }
            }
            __syncthreads();
            size_t base = (size_t)c * N;
            for (int j = tid; j < RANGE; j += BD) {
                int node = lo + j;
                if (node < N) partial[base + node] = table[j];
            }
            __syncthreads();
        }
    }
    gridg.sync();   // SYNC 3

    // ---------------- Phase D: per-graph reduce + double softmax -----------
    // acc[node] = dinv*(g + sum_c partial) — graph-local, no extra sync.
    for (int g = b; g < G; g += NB) {
        int part = 0;
        for (int j = tid; j < g; j += BD) part += splitn[j];
        ired[tid] = part; __syncthreads();
        for (int s = BD / 2; s > 0; s >>= 1) {
            if (tid < s) ired[tid] += ired[tid + s];
            __syncthreads();
        }
        if (tid == 0) sh_off = ired[0];
        __syncthreads();
        const int off = sh_off;
        const int cnt = splitn[g];
        const bool fits = (cnt <= RANGE);

        if (fits) {
            for (int j = tid; j < cnt; j += BD) {
                int node = off + j;
                float s = hbuf[node];
                for (int c = 0; c < C; ++c) s += partial[(size_t)c * N + node];
                table[j] = dv1[node] * s;
            }
        } else {
            for (int j = tid; j < cnt; j += BD) {
                int node = off + j;
                float s = hbuf[node];
                for (int c = 0; c < C; ++c) s += partial[(size_t)c * N + node];
                accfb[node] = dv1[node] * s;
            }
        }
        __syncthreads();

        // softmax #1
        float mx = -INFINITY;
        for (int j = tid; j < cnt; j += BD)
            mx = fmaxf(mx, fits ? table[j] : accfb[off + j]);
        red[tid] = mx; __syncthreads();
        for (int s = BD / 2; s > 0; s >>= 1) {
            if (tid < s) red[tid] = fmaxf(red[tid], red[tid + s]);
            __syncthreads();
        }
        mx = red[0]; __syncthreads();
        float sum = 0.f;
        for (int j = tid; j < cnt; j += BD)
            sum += expf((fits ? table[j] : accfb[off + j]) - mx);
        red[tid] = sum; __syncthreads();
        for (int s = BD / 2; s > 0; s >>= 1) {
            if (tid < s) red[tid] += red[tid + s];
            __syncthreads();
        }
        const float inv1 = 1.0f / red[0]; __syncthreads();
        for (int j = tid; j < cnt; j += BD) {
            float mv = expf((fits ? table[j] : accfb[off + j]) - mx) * inv1;
            node_m[off + j] = mv;
            if (fits) table[j] = mv;
        }
        __syncthreads();

        // softmax #2 over (1 - m)
        float mx2 = -INFINITY;
        for (int j = tid; j < cnt; j += BD)
            mx2 = fmaxf(mx2, 1.0f - (fits ? table[j] : node_m[off + j]));
        red[tid] = mx2; __syncthreads();
        for (int s = BD / 2; s > 0; s >>= 1) {
            if (tid < s) red[tid] = fmaxf(red[tid], red[tid + s]);
            __syncthreads();
        }
        mx2 = red[0]; __syncthreads();
        float sum2 = 0.f;
        for (int j = tid; j < cnt; j += BD)
            sum2 += expf(1.0f - (fits ? table[j] : node_m[off + j]) - mx2);
        red[tid] = sum2; __syncthreads();
        for (int s = BD / 2; s > 0; s >>= 1) {
            if (tid < s) red[tid] += red[tid + s];
            __syncthreads();
        }
        const float inv2 = 1.0f / red[0]; __syncthreads();
        for (int j = tid; j < cnt; j += BD)
            node_s[off + j] = expf(1.0f - (fits ? table[j] : node_m[off + j]) - mx2) * inv2;
        __syncthreads();   // table/ired/sh_off reused next graph
    }
}

extern "C" void kernel_launch(void* const* d_in, const int* in_sizes, int n_in,
                              void* d_out, int out_size, void* d_ws, size_t ws_size,
                              hipStream_t stream) {
    const float* x      = (const float*)d_in[0];
    const int*   ei     = (const int*)d_in[1];
    const int*   splitn = (const int*)d_in[2];
    const float* W_edge = (const float*)d_in[3];
    const float* b_edge = (const float*)d_in[4];
    const float* W_gcn  = (const float*)d_in[5];

    const int N = in_sizes[0] / 64;
    const int E = in_sizes[1] / 2;
    const int G = in_sizes[2];

    float* out = (float*)d_out;
    float* edge_m = out;
    float* edge_s = out + E;
    float* node_m = out + 2LL * E;
    float* node_s = out + 2LL * E + N;

    // C edge-chunks (multiple of 8); shrink if ws is small.
    int C = 64;
    while (C > 8 && (size_t)(5 + C) * N * sizeof(float) > ws_size) C >>= 1;
    const int R  = (N + RANGE - 1) / RANGE;
    const int CH = (((E + C - 1) / C) + 3) & ~3;
    const int vec = ((E & 3) == 0) ? 1 : 0;

    float2* ed2     = (float2*)d_ws;
    float*  hbuf    = (float*)d_ws + 2LL * N;
    float*  dv1     = hbuf + N;
    float*  accfb   = dv1 + N;
    float*  partial = accfb + N;

    // co-resident grid for cooperative launch
    int dev = 0;
    hipGetDevice(&dev);
    int numCU = 0;
    hipDeviceGetAttribute(&numCU, hipDeviceAttributeMultiprocessorCount, dev);
    if (numCU <= 0) numCU = 256;
    int perCU = 0;
    hipOccupancyMaxActiveBlocksPerMultiprocessor(&perCU, k_fused, BD, 0);
    if (perCU < 1) perCU = 1;
    long long nb = (long long)numCU * perCU;
    if (nb > 2048) nb = 2048;
    int NB = (int)(nb & ~7LL);
    if (NB < 8) NB = 8;

    int n = N, e = E, g = G, c = C, r = R, ch = CH, v = vec;
    void* args[] = {
        (void*)&x, (void*)&ei, (void*)&splitn, (void*)&W_edge, (void*)&b_edge,
        (void*)&W_gcn, (void*)&edge_m, (void*)&edge_s, (void*)&node_m,
        (void*)&node_s, (void*)&ed2, (void*)&hbuf, (void*)&dv1, (void*)&accfb,
        (void*)&partial, (void*)&n, (void*)&e, (void*)&g, (void*)&c, (void*)&r,
        (void*)&ch, (void*)&v
    };
    hipLaunchCooperativeKernel(k_fused, dim3(NB), dim3(BD), args, 0, stream);
}

// Round 6
// 102.995 us; speedup vs baseline: 3.8735x; 3.8735x over previous
//
#include <hip/hip_runtime.h>
#include <math.h>

// ---------------------------------------------------------------------------
// Att_cov, round 6: back to multi-kernel (coop grid.sync was ~100us/sync).
// Minimum dependency chain, 4 kernels:
//  k1: node projections (pa,pb,h)  ||  partitioned degree histogram
//  k2: dinv (g=h*dinv, dv1)        ||  edge sigmoid outputs
//  k3: partitioned GCN scatter (table[col-lo] += g[row])
//  k4: per-graph fused partial-reduce + two chained ragged softmaxes
// Partition scheme: nodes in R ranges of RANGE=8192 (32KB LDS table), edges
// in C chunks; block (r,c) scans chunk c's col stream (L2-resident), bins
// in-range hits with LDS atomics, writes slice to partial[c][*] with plain
// stores. Zero global atomics anywhere.
// ws (floats): ed2[2N] | hbuf[N] (h->g) | dv1[N] | accfb[N] | partial[C*N]
// ---------------------------------------------------------------------------

#define RANGE 8192
#define SOFT_LDS_CAP 2048

// k1: blocks [0,nodeBlocks) project nodes; blocks [nodeBlocks, +R*C) histogram.
__global__ __launch_bounds__(256)
void k1_node_hist(const float* __restrict__ x,
                  const float* __restrict__ W_edge,
                  const float* __restrict__ W_gcn,
                  const int* __restrict__ ei,
                  float2* __restrict__ ed2,
                  float* __restrict__ hbuf,
                  float* __restrict__ partial,
                  int N, int E, int C, int R, int CH, int nodeBlocks, int vec) {
    const int bid = blockIdx.x, tid = threadIdx.x;
    if (bid < nodeBlocks) {
        __shared__ float4 Wa[16], Wb[16], Wg[16];
        if (tid < 16) {
            Wa[tid] = ((const float4*)W_edge)[tid];
            Wb[tid] = ((const float4*)W_edge)[16 + tid];
            Wg[tid] = ((const float4*)W_gcn)[tid];
        }
        __syncthreads();
        int lane = tid & 15;
        long long gid = (long long)bid * 256 + tid;
        int i = (int)(gid >> 4);
        if (i >= N) return;
        float4 v = ((const float4*)(x + (size_t)i * 64))[lane];
        float4 wa = Wa[lane], wb = Wb[lane], wg = Wg[lane];
        float p1 = v.x*wa.x + v.y*wa.y + v.z*wa.z + v.w*wa.w;
        float p2 = v.x*wb.x + v.y*wb.y + v.z*wb.z + v.w*wb.w;
        float p3 = v.x*wg.x + v.y*wg.y + v.z*wg.z + v.w*wg.w;
#pragma unroll
        for (int s = 1; s < 16; s <<= 1) {
            p1 += __shfl_xor(p1, s);
            p2 += __shfl_xor(p2, s);
            p3 += __shfl_xor(p3, s);
        }
        if (lane == 0) {
            ed2[i] = make_float2(p1, p2);
            hbuf[i] = p3;
        }
        return;
    }
    __shared__ float table[RANGE];
    const int hb = bid - nodeBlocks;
    const int c = hb / R;
    const int r = hb - c * R;
    const int lo = r * RANGE;
    for (int j = tid; j < RANGE; j += 256) table[j] = 0.f;
    __syncthreads();
    const int e_lo = c * CH;
    const int e_hi = (E < e_lo + CH) ? E : (e_lo + CH);
    const int* __restrict__ col = ei + E;
    for (int e = e_lo + tid * 4; e < e_hi; e += 256 * 4) {
        if (vec && e + 3 < e_hi) {
            int4 cc = *(const int4*)(col + e);
            unsigned u;
            u = (unsigned)(cc.x - lo); if (u < RANGE) atomicAdd(&table[u], 1.f);
            u = (unsigned)(cc.y - lo); if (u < RANGE) atomicAdd(&table[u], 1.f);
            u = (unsigned)(cc.z - lo); if (u < RANGE) atomicAdd(&table[u], 1.f);
            u = (unsigned)(cc.w - lo); if (u < RANGE) atomicAdd(&table[u], 1.f);
        } else {
            int ee = (e_hi < e + 4) ? e_hi : e + 4;
            for (int q = e; q < ee; ++q) {
                unsigned u = (unsigned)(col[q] - lo);
                if (u < RANGE) atomicAdd(&table[u], 1.f);
            }
        }
    }
    __syncthreads();
    const size_t base = (size_t)c * N;
    for (int j = tid; j < RANGE; j += 256) {
        int node = lo + j;
        if (node < N) partial[base + node] = table[j];
    }
}

// k2: blocks [0,dinvBlocks) compute dinv & g; rest do edge sigmoid.
__global__ __launch_bounds__(256)
void k2_dinv_sig(const int* __restrict__ ei,
                 const float2* __restrict__ ed2,
                 const float* __restrict__ b_edge,
                 const float* __restrict__ partial,
                 float* __restrict__ hbuf,       // in: h, out: g = h*dinv
                 float* __restrict__ dv1,
                 float* __restrict__ om, float* __restrict__ os,
                 int N, int E, int C, int dinvBlocks, int vec) {
    const int bid = blockIdx.x, tid = threadIdx.x;
    if (bid < dinvBlocks) {
        int i = bid * 256 + tid;
        if (i >= N) return;
        float deg = 1.f;  // self-loop
        for (int c = 0; c < C; ++c) deg += partial[(size_t)c * N + i];
        float dv = rsqrtf(deg);
        hbuf[i] *= dv;
        dv1[i] = dv;
        return;
    }
    int t = (bid - dinvBlocks) * 256 + tid;
    int e0 = t * 4;
    const float b = b_edge[0];
    if (vec && e0 + 3 < E) {
        int4 r = *(const int4*)(ei + e0);
        int4 c = *(const int4*)(ei + E + e0);
        float4 m;
        m.x = 1.f / (1.f + expf(-(ed2[r.x].x + ed2[c.x].y + b)));
        m.y = 1.f / (1.f + expf(-(ed2[r.y].x + ed2[c.y].y + b)));
        m.z = 1.f / (1.f + expf(-(ed2[r.z].x + ed2[c.z].y + b)));
        m.w = 1.f / (1.f + expf(-(ed2[r.w].x + ed2[c.w].y + b)));
        *(float4*)(om + e0) = m;
        *(float4*)(os + e0) = make_float4(1.f - m.x, 1.f - m.y, 1.f - m.z, 1.f - m.w);
    } else if (e0 < E) {
        int ee = (E < e0 + 4) ? E : e0 + 4;
        for (int e = e0; e < ee; ++e) {
            float a = 1.f / (1.f + expf(-(ed2[ei[e]].x + ed2[ei[E + e]].y + b)));
            om[e] = a; os[e] = 1.f - a;
        }
    }
}

// k3: partitioned scatter; row gathered only on in-range hit.
__global__ __launch_bounds__(256)
void k3_scat(const int* __restrict__ ei,
             const float* __restrict__ g1,
             float* __restrict__ partial,
             int N, int E, int C, int R, int CH, int vec) {
    __shared__ float table[RANGE];
    const int tid = threadIdx.x;
    const int c = blockIdx.x / R;
    const int r = blockIdx.x - c * R;
    const int lo = r * RANGE;
    for (int j = tid; j < RANGE; j += 256) table[j] = 0.f;
    __syncthreads();
    const int e_lo = c * CH;
    const int e_hi = (E < e_lo + CH) ? E : (e_lo + CH);
    const int* __restrict__ row = ei;
    const int* __restrict__ col = ei + E;
    for (int e = e_lo + tid * 4; e < e_hi; e += 256 * 4) {
        if (vec && e + 3 < e_hi) {
            int4 cc = *(const int4*)(col + e);
            unsigned u;
            u = (unsigned)(cc.x - lo); if (u < RANGE) atomicAdd(&table[u], g1[row[e + 0]]);
            u = (unsigned)(cc.y - lo); if (u < RANGE) atomicAdd(&table[u], g1[row[e + 1]]);
            u = (unsigned)(cc.z - lo); if (u < RANGE) atomicAdd(&table[u], g1[row[e + 2]]);
            u = (unsigned)(cc.w - lo); if (u < RANGE) atomicAdd(&table[u], g1[row[e + 3]]);
        } else {
            int ee = (e_hi < e + 4) ? e_hi : e + 4;
            for (int q = e; q < ee; ++q) {
                unsigned u = (unsigned)(col[q] - lo);
                if (u < RANGE) atomicAdd(&table[u], g1[row[q]]);
            }
        }
    }
    __syncthreads();
    const size_t base = (size_t)c * N;
    for (int j = tid; j < RANGE; j += 256) {
        int node = lo + j;
        if (node < N) partial[base + node] = table[j];
    }
}

// k4: one block/graph; fused partial-reduce + two chained ragged softmaxes.
// acc[node] = dv1*(g + sum_c partial[c][node]); b_gcn omitted (shift-inv).
__global__ __launch_bounds__(128)
void k4_softmax(const float* __restrict__ hbuf,   // g
                const float* __restrict__ dv1,
                const float* __restrict__ partial,
                float* __restrict__ accfb,
                const int* __restrict__ split_n,
                float* __restrict__ out_m, float* __restrict__ out_s,
                int N, int C) {
    __shared__ float red[128];
    __shared__ int ired[128];
    __shared__ int sh_off;
    __shared__ float sv[SOFT_LDS_CAP];
    const int g = blockIdx.x;
    const int tid = threadIdx.x;
    const int BD = blockDim.x;

    int part = 0;
    for (int j = tid; j < g; j += BD) part += split_n[j];
    ired[tid] = part; __syncthreads();
    for (int s = 64; s > 0; s >>= 1) {
        if (tid < s) ired[tid] += ired[tid + s];
        __syncthreads();
    }
    if (tid == 0) sh_off = ired[0];
    __syncthreads();
    const int off = sh_off;
    const int cnt = split_n[g];
    const bool fits = (cnt <= SOFT_LDS_CAP);

    for (int j = tid; j < cnt; j += BD) {
        int node = off + j;
        float s = hbuf[node];
        for (int c = 0; c < C; ++c) s += partial[(size_t)c * N + node];
        float a = dv1[node] * s;
        if (fits) sv[j] = a; else accfb[node] = a;
    }
    __syncthreads();

    // softmax #1
    float mx = -INFINITY;
    for (int j = tid; j < cnt; j += BD) mx = fmaxf(mx, fits ? sv[j] : accfb[off + j]);
    red[tid] = mx; __syncthreads();
    for (int s = 64; s > 0; s >>= 1) {
        if (tid < s) red[tid] = fmaxf(red[tid], red[tid + s]);
        __syncthreads();
    }
    mx = red[0]; __syncthreads();
    float sum = 0.f;
    for (int j = tid; j < cnt; j += BD) sum += expf((fits ? sv[j] : accfb[off + j]) - mx);
    red[tid] = sum; __syncthreads();
    for (int s = 64; s > 0; s >>= 1) {
        if (tid < s) red[tid] += red[tid + s];
        __syncthreads();
    }
    const float inv1 = 1.0f / red[0]; __syncthreads();
    for (int j = tid; j < cnt; j += BD) {
        float mv = expf((fits ? sv[j] : accfb[off + j]) - mx) * inv1;
        out_m[off + j] = mv;
        if (fits) sv[j] = mv;
    }
    __syncthreads();

    // softmax #2 over (1 - m)
    float mx2 = -INFINITY;
    for (int j = tid; j < cnt; j += BD)
        mx2 = fmaxf(mx2, 1.0f - (fits ? sv[j] : out_m[off + j]));
    red[tid] = mx2; __syncthreads();
    for (int s = 64; s > 0; s >>= 1) {
        if (tid < s) red[tid] = fmaxf(red[tid], red[tid + s]);
        __syncthreads();
    }
    mx2 = red[0]; __syncthreads();
    float sum2 = 0.f;
    for (int j = tid; j < cnt; j += BD)
        sum2 += expf(1.0f - (fits ? sv[j] : out_m[off + j]) - mx2);
    red[tid] = sum2; __syncthreads();
    for (int s = 64; s > 0; s >>= 1) {
        if (tid < s) red[tid] += red[tid + s];
        __syncthreads();
    }
    const float inv2 = 1.0f / red[0]; __syncthreads();
    for (int j = tid; j < cnt; j += BD)
        out_s[off + j] = expf(1.0f - (fits ? sv[j] : out_m[off + j]) - mx2) * inv2;
}

extern "C" void kernel_launch(void* const* d_in, const int* in_sizes, int n_in,
                              void* d_out, int out_size, void* d_ws, size_t ws_size,
                              hipStream_t stream) {
    const float* x      = (const float*)d_in[0];
    const int*   ei     = (const int*)d_in[1];
    const int*   splitn = (const int*)d_in[2];
    const float* W_edge = (const float*)d_in[3];
    const float* b_edge = (const float*)d_in[4];
    const float* W_gcn  = (const float*)d_in[5];

    const int N = in_sizes[0] / 64;
    const int E = in_sizes[1] / 2;
    const int G = in_sizes[2];

    float* out = (float*)d_out;
    float* edge_m = out;
    float* edge_s = out + E;
    float* node_m = out + 2LL * E;
    float* node_s = out + 2LL * E + N;

    int C = 32;
    while (C > 2 && (size_t)(5 + C) * N * sizeof(float) > ws_size) C >>= 1;
    const int R  = (N + RANGE - 1) / RANGE;
    const int CH = (((E + C - 1) / C) + 3) & ~3;
    const int vec = ((E & 3) == 0) ? 1 : 0;

    float2* ed2     = (float2*)d_ws;
    float*  hbuf    = (float*)d_ws + 2LL * N;
    float*  dv1     = hbuf + N;
    float*  accfb   = dv1 + N;
    float*  partial = accfb + N;

    const int nodeBlocks = (N * 16 + 255) / 256;
    const int dinvBlocks = (N + 255) / 256;
    const int sigBlocks  = ((E + 3) / 4 + 255) / 256;

    k1_node_hist<<<nodeBlocks + R * C, 256, 0, stream>>>(
        x, W_edge, W_gcn, ei, ed2, hbuf, partial, N, E, C, R, CH, nodeBlocks, vec);
    k2_dinv_sig<<<dinvBlocks + sigBlocks, 256, 0, stream>>>(
        ei, ed2, b_edge, partial, hbuf, dv1, edge_m, edge_s, N, E, C, dinvBlocks, vec);
    k3_scat<<<R * C, 256, 0, stream>>>(ei, hbuf, partial, N, E, C, R, CH, vec);
    k4_softmax<<<G, 128, 0, stream>>>(hbuf, dv1, partial, accfb, splitn,
                                      node_m, node_s, N, C);
}

// Round 7
// 55.996 us; speedup vs baseline: 7.1247x; 1.8393x over previous
//
#include <hip/hip_runtime.h>
#include <math.h>

// ---------------------------------------------------------------------------
// Att_cov, round 7: round-6 skeleton (4 kernels, zero global atomics) with
// the scatter/histogram parallelism fixed:
//   BD_H=1024 threads (16 waves) per hist/scat block, C=64 edge chunks,
//   RANGE=8192 (32KB LDS) -> R=7 ranges, grid R*C=448, ~32 waves/CU.
//  k1: node projections (pa,pb,h)  ||  partitioned degree histogram
//  k2: dinv (g=h*dinv, dv1)        ||  edge sigmoid outputs
//  k3: partitioned GCN scatter (table[col-lo] += g[row]), int4 row loads
//  k4: per-graph fused partial-reduce + two chained ragged softmaxes
// ws (floats): ed2[2N] | hbuf[N] (h->g) | dv1[N] | accfb[N] | partial[C*N]
// ---------------------------------------------------------------------------

#define RANGE 8192
#define BD_H 1024
#define SOFT_LDS_CAP 2048

// k1: blocks [0,nodeBlocks) project nodes; blocks [nodeBlocks, +R*C) histogram.
__global__ __launch_bounds__(BD_H)
void k1_node_hist(const float* __restrict__ x,
                  const float* __restrict__ W_edge,
                  const float* __restrict__ W_gcn,
                  const int* __restrict__ ei,
                  float2* __restrict__ ed2,
                  float* __restrict__ hbuf,
                  float* __restrict__ partial,
                  int N, int E, int C, int R, int CH, int nodeBlocks, int vec) {
    __shared__ float table[RANGE];           // hist table; aliased as W cache
    const int bid = blockIdx.x, tid = threadIdx.x;
    if (bid < nodeBlocks) {
        float4* Wsh = (float4*)table;        // [0..15]=Wa [16..31]=Wb [32..47]=Wg
        if (tid < 32) Wsh[tid] = ((const float4*)W_edge)[tid];
        else if (tid < 48) Wsh[tid] = ((const float4*)W_gcn)[tid - 32];
        __syncthreads();
        int lane = tid & 15;
        long long gid = (long long)bid * BD_H + tid;
        int i = (int)(gid >> 4);
        if (i >= N) return;
        float4 v = ((const float4*)(x + (size_t)i * 64))[lane];
        float4 wa = Wsh[lane], wb = Wsh[16 + lane], wg = Wsh[32 + lane];
        float p1 = v.x*wa.x + v.y*wa.y + v.z*wa.z + v.w*wa.w;
        float p2 = v.x*wb.x + v.y*wb.y + v.z*wb.z + v.w*wb.w;
        float p3 = v.x*wg.x + v.y*wg.y + v.z*wg.z + v.w*wg.w;
#pragma unroll
        for (int s = 1; s < 16; s <<= 1) {
            p1 += __shfl_xor(p1, s);
            p2 += __shfl_xor(p2, s);
            p3 += __shfl_xor(p3, s);
        }
        if (lane == 0) {
            ed2[i] = make_float2(p1, p2);
            hbuf[i] = p3;
        }
        return;
    }
    const int hb = bid - nodeBlocks;
    const int c = hb / R;
    const int r = hb - c * R;
    const int lo = r * RANGE;
    for (int j = tid; j < RANGE; j += BD_H) table[j] = 0.f;
    __syncthreads();
    const int e_lo = c * CH;
    const int e_hi = (E < e_lo + CH) ? E : (e_lo + CH);
    const int* __restrict__ col = ei + E;
    for (int e = e_lo + tid * 4; e < e_hi; e += BD_H * 4) {
        if (vec && e + 3 < e_hi) {
            int4 cc = *(const int4*)(col + e);
            unsigned u;
            u = (unsigned)(cc.x - lo); if (u < RANGE) atomicAdd(&table[u], 1.f);
            u = (unsigned)(cc.y - lo); if (u < RANGE) atomicAdd(&table[u], 1.f);
            u = (unsigned)(cc.z - lo); if (u < RANGE) atomicAdd(&table[u], 1.f);
            u = (unsigned)(cc.w - lo); if (u < RANGE) atomicAdd(&table[u], 1.f);
        } else {
            int ee = (e_hi < e + 4) ? e_hi : e + 4;
            for (int q = e; q < ee; ++q) {
                unsigned u = (unsigned)(col[q] - lo);
                if (u < RANGE) atomicAdd(&table[u], 1.f);
            }
        }
    }
    __syncthreads();
    const size_t base = (size_t)c * N;
    for (int j = tid; j < RANGE; j += BD_H) {
        int node = lo + j;
        if (node < N) partial[base + node] = table[j];
    }
}

// k2: blocks [0,dinvBlocks) compute dinv & g; rest do edge sigmoid.
__global__ __launch_bounds__(256)
void k2_dinv_sig(const int* __restrict__ ei,
                 const float2* __restrict__ ed2,
                 const float* __restrict__ b_edge,
                 const float* __restrict__ partial,
                 float* __restrict__ hbuf,       // in: h, out: g = h*dinv
                 float* __restrict__ dv1,
                 float* __restrict__ om, float* __restrict__ os,
                 int N, int E, int C, int dinvBlocks, int vec) {
    const int bid = blockIdx.x, tid = threadIdx.x;
    if (bid < dinvBlocks) {
        int i = bid * 256 + tid;
        if (i >= N) return;
        float d0 = 1.f, d1 = 0.f, d2 = 0.f, d3 = 0.f;   // self-loop in d0
        int c = 0;
        for (; c + 3 < C; c += 4) {
            d0 += partial[(size_t)(c + 0) * N + i];
            d1 += partial[(size_t)(c + 1) * N + i];
            d2 += partial[(size_t)(c + 2) * N + i];
            d3 += partial[(size_t)(c + 3) * N + i];
        }
        for (; c < C; ++c) d0 += partial[(size_t)c * N + i];
        float dv = rsqrtf((d0 + d1) + (d2 + d3));
        hbuf[i] *= dv;
        dv1[i] = dv;
        return;
    }
    int t = (bid - dinvBlocks) * 256 + tid;
    int e0 = t * 4;
    const float b = b_edge[0];
    if (vec && e0 + 3 < E) {
        int4 r = *(const int4*)(ei + e0);
        int4 c = *(const int4*)(ei + E + e0);
        float4 m;
        m.x = 1.f / (1.f + expf(-(ed2[r.x].x + ed2[c.x].y + b)));
        m.y = 1.f / (1.f + expf(-(ed2[r.y].x + ed2[c.y].y + b)));
        m.z = 1.f / (1.f + expf(-(ed2[r.z].x + ed2[c.z].y + b)));
        m.w = 1.f / (1.f + expf(-(ed2[r.w].x + ed2[c.w].y + b)));
        *(float4*)(om + e0) = m;
        *(float4*)(os + e0) = make_float4(1.f - m.x, 1.f - m.y, 1.f - m.z, 1.f - m.w);
    } else if (e0 < E) {
        int ee = (E < e0 + 4) ? E : e0 + 4;
        for (int e = e0; e < ee; ++e) {
            float a = 1.f / (1.f + expf(-(ed2[ei[e]].x + ed2[ei[E + e]].y + b)));
            om[e] = a; os[e] = 1.f - a;
        }
    }
}

// k3: partitioned scatter; unconditional int4 row loads (stream, L2-resident),
// conditional g1 gathers only on in-range hits.
__global__ __launch_bounds__(BD_H)
void k3_scat(const int* __restrict__ ei,
             const float* __restrict__ g1,
             float* __restrict__ partial,
             int N, int E, int C, int R, int CH, int vec) {
    __shared__ float table[RANGE];
    const int tid = threadIdx.x;
    const int c = blockIdx.x / R;
    const int r = blockIdx.x - c * R;
    const int lo = r * RANGE;
    for (int j = tid; j < RANGE; j += BD_H) table[j] = 0.f;
    __syncthreads();
    const int e_lo = c * CH;
    const int e_hi = (E < e_lo + CH) ? E : (e_lo + CH);
    const int* __restrict__ row = ei;
    const int* __restrict__ col = ei + E;
    for (int e = e_lo + tid * 4; e < e_hi; e += BD_H * 4) {
        if (vec && e + 3 < e_hi) {
            int4 cc = *(const int4*)(col + e);
            int4 rr = *(const int4*)(row + e);
            unsigned u;
            u = (unsigned)(cc.x - lo); if (u < RANGE) atomicAdd(&table[u], g1[rr.x]);
            u = (unsigned)(cc.y - lo); if (u < RANGE) atomicAdd(&table[u], g1[rr.y]);
            u = (unsigned)(cc.z - lo); if (u < RANGE) atomicAdd(&table[u], g1[rr.z]);
            u = (unsigned)(cc.w - lo); if (u < RANGE) atomicAdd(&table[u], g1[rr.w]);
        } else {
            int ee = (e_hi < e + 4) ? e_hi : e + 4;
            for (int q = e; q < ee; ++q) {
                unsigned u = (unsigned)(col[q] - lo);
                if (u < RANGE) atomicAdd(&table[u], g1[row[q]]);
            }
        }
    }
    __syncthreads();
    const size_t base = (size_t)c * N;
    for (int j = tid; j < RANGE; j += BD_H) {
        int node = lo + j;
        if (node < N) partial[base + node] = table[j];
    }
}

// k4: one block/graph; fused partial-reduce + two chained ragged softmaxes.
// acc[node] = dv1*(g + sum_c partial[c][node]); b_gcn omitted (shift-inv).
__global__ __launch_bounds__(128)
void k4_softmax(const float* __restrict__ hbuf,   // g
                const float* __restrict__ dv1,
                const float* __restrict__ partial,
                float* __restrict__ accfb,
                const int* __restrict__ split_n,
                float* __restrict__ out_m, float* __restrict__ out_s,
                int N, int C) {
    __shared__ float red[128];
    __shared__ int ired[128];
    __shared__ int sh_off;
    __shared__ float sv[SOFT_LDS_CAP];
    const int g = blockIdx.x;
    const int tid = threadIdx.x;
    const int BD = blockDim.x;

    int part = 0;
    for (int j = tid; j < g; j += BD) part += split_n[j];
    ired[tid] = part; __syncthreads();
    for (int s = 64; s > 0; s >>= 1) {
        if (tid < s) ired[tid] += ired[tid + s];
        __syncthreads();
    }
    if (tid == 0) sh_off = ired[0];
    __syncthreads();
    const int off = sh_off;
    const int cnt = split_n[g];
    const bool fits = (cnt <= SOFT_LDS_CAP);

    for (int j = tid; j < cnt; j += BD) {
        int node = off + j;
        float s0 = hbuf[node], s1 = 0.f, s2 = 0.f, s3 = 0.f;
        int c = 0;
        for (; c + 3 < C; c += 4) {
            s0 += partial[(size_t)(c + 0) * N + node];
            s1 += partial[(size_t)(c + 1) * N + node];
            s2 += partial[(size_t)(c + 2) * N + node];
            s3 += partial[(size_t)(c + 3) * N + node];
        }
        for (; c < C; ++c) s0 += partial[(size_t)c * N + node];
        float a = dv1[node] * ((s0 + s1) + (s2 + s3));
        if (fits) sv[j] = a; else accfb[node] = a;
    }
    __syncthreads();

    // softmax #1
    float mx = -INFINITY;
    for (int j = tid; j < cnt; j += BD) mx = fmaxf(mx, fits ? sv[j] : accfb[off + j]);
    red[tid] = mx; __syncthreads();
    for (int s = 64; s > 0; s >>= 1) {
        if (tid < s) red[tid] = fmaxf(red[tid], red[tid + s]);
        __syncthreads();
    }
    mx = red[0]; __syncthreads();
    float sum = 0.f;
    for (int j = tid; j < cnt; j += BD) sum += expf((fits ? sv[j] : accfb[off + j]) - mx);
    red[tid] = sum; __syncthreads();
    for (int s = 64; s > 0; s >>= 1) {
        if (tid < s) red[tid] += red[tid + s];
        __syncthreads();
    }
    const float inv1 = 1.0f / red[0]; __syncthreads();
    for (int j = tid; j < cnt; j += BD) {
        float mv = expf((fits ? sv[j] : accfb[off + j]) - mx) * inv1;
        out_m[off + j] = mv;
        if (fits) sv[j] = mv;
    }
    __syncthreads();

    // softmax #2 over (1 - m)
    float mx2 = -INFINITY;
    for (int j = tid; j < cnt; j += BD)
        mx2 = fmaxf(mx2, 1.0f - (fits ? sv[j] : out_m[off + j]));
    red[tid] = mx2; __syncthreads();
    for (int s = 64; s > 0; s >>= 1) {
        if (tid < s) red[tid] = fmaxf(red[tid], red[tid + s]);
        __syncthreads();
    }
    mx2 = red[0]; __syncthreads();
    float sum2 = 0.f;
    for (int j = tid; j < cnt; j += BD)
        sum2 += expf(1.0f - (fits ? sv[j] : out_m[off + j]) - mx2);
    red[tid] = sum2; __syncthreads();
    for (int s = 64; s > 0; s >>= 1) {
        if (tid < s) red[tid] += red[tid + s];
        __syncthreads();
    }
    const float inv2 = 1.0f / red[0]; __syncthreads();
    for (int j = tid; j < cnt; j += BD)
        out_s[off + j] = expf(1.0f - (fits ? sv[j] : out_m[off + j]) - mx2) * inv2;
}

extern "C" void kernel_launch(void* const* d_in, const int* in_sizes, int n_in,
                              void* d_out, int out_size, void* d_ws, size_t ws_size,
                              hipStream_t stream) {
    const float* x      = (const float*)d_in[0];
    const int*   ei     = (const int*)d_in[1];
    const int*   splitn = (const int*)d_in[2];
    const float* W_edge = (const float*)d_in[3];
    const float* b_edge = (const float*)d_in[4];
    const float* W_gcn  = (const float*)d_in[5];

    const int N = in_sizes[0] / 64;
    const int E = in_sizes[1] / 2;
    const int G = in_sizes[2];

    float* out = (float*)d_out;
    float* edge_m = out;
    float* edge_s = out + E;
    float* node_m = out + 2LL * E;
    float* node_s = out + 2LL * E + N;

    int C = 64;
    while (C > 2 && (size_t)(5 + C) * N * sizeof(float) > ws_size) C >>= 1;
    const int R  = (N + RANGE - 1) / RANGE;
    const int CH = (((E + C - 1) / C) + 3) & ~3;
    const int vec = ((E & 3) == 0) ? 1 : 0;

    float2* ed2     = (float2*)d_ws;
    float*  hbuf    = (float*)d_ws + 2LL * N;
    float*  dv1     = hbuf + N;
    float*  accfb   = dv1 + N;
    float*  partial = accfb + N;

    const int nodeBlocks = (int)(((long long)N * 16 + BD_H - 1) / BD_H);
    const int dinvBlocks = (N + 255) / 256;
    const int sigBlocks  = ((E + 3) / 4 + 255) / 256;

    k1_node_hist<<<nodeBlocks + R * C, BD_H, 0, stream>>>(
        x, W_edge, W_gcn, ei, ed2, hbuf, partial, N, E, C, R, CH, nodeBlocks, vec);
    k2_dinv_sig<<<dinvBlocks + sigBlocks, 256, 0, stream>>>(
        ei, ed2, b_edge, partial, hbuf, dv1, edge_m, edge_s, N, E, C, dinvBlocks, vec);
    k3_scat<<<R * C, BD_H, 0, stream>>>(ei, hbuf, partial, N, E, C, R, CH, vec);
    k4_softmax<<<G, 128, 0, stream>>>(hbuf, dv1, partial, accfb, splitn,
                                      node_m, node_s, N, C);
}

// Round 8
// 50.780 us; speedup vs baseline: 7.8566x; 1.1027x over previous
//
#include <hip/hip_runtime.h>
#include <math.h>

// ---------------------------------------------------------------------------
// Att_cov, round 8: r7 skeleton (4 kernels, zero global atomics) +
//  - u16-packed degree histogram: RANGE_H=16384 in 32KB LDS (paired u16 in
//    u32 words, LDS u32 atomics; per-chunk counts < 65536 so no overflow),
//    R_h=4 col scans (was 7), deg-partial is u16 (6.4MB, was 12.8 f32).
//  - pa[]/pb[] split (4B sigmoid gathers instead of 8B float2).
//  - k3 scatter unchanged from r7 (proven: RANGE_S=8192 f32, 1024 thr).
// Chain: k1{proj || u16-hist} -> k2{dinv || sigmoid} -> k3{scatter} ->
//        k4{fused partial-reduce + double ragged softmax}.
// ws (floats): pa[N] | pb[N] | hbuf[N] (h->g) | dv1[N] | accfb[N] |
//              partial[Cs*N f32]  (aliased first as u16 deg-partial [Ch*N])
// ---------------------------------------------------------------------------

#define RANGE_S 8192
#define RANGE_H 16384
#define BD_H 1024
#define SOFT_LDS_CAP 2048

typedef unsigned short u16t;
typedef unsigned int u32t;

// k1: blocks [0,nodeBlocks) project nodes; blocks [nodeBlocks,+Rh*Ch) histogram.
__global__ __launch_bounds__(BD_H)
void k1_node_hist(const float* __restrict__ x,
                  const float* __restrict__ W_edge,
                  const float* __restrict__ W_gcn,
                  const int* __restrict__ ei,
                  float* __restrict__ pa, float* __restrict__ pb,
                  float* __restrict__ hbuf,
                  u16t* __restrict__ pd,
                  int N, int E, int Ch, int Rh, int CHh, int nodeBlocks, int vec) {
    __shared__ u32t t32[RANGE_H / 2];       // 32KB; aliased as W cache for proj
    const int bid = blockIdx.x, tid = threadIdx.x;
    if (bid < nodeBlocks) {
        float4* Wsh = (float4*)t32;         // [0..15]=Wa [16..31]=Wb [32..47]=Wg
        if (tid < 32) Wsh[tid] = ((const float4*)W_edge)[tid];
        else if (tid < 48) Wsh[tid] = ((const float4*)W_gcn)[tid - 32];
        __syncthreads();
        int lane = tid & 15;
        long long gid = (long long)bid * BD_H + tid;
        int i = (int)(gid >> 4);
        if (i >= N) return;
        float4 v = ((const float4*)(x + (size_t)i * 64))[lane];
        float4 wa = Wsh[lane], wb = Wsh[16 + lane], wg = Wsh[32 + lane];
        float p1 = v.x*wa.x + v.y*wa.y + v.z*wa.z + v.w*wa.w;
        float p2 = v.x*wb.x + v.y*wb.y + v.z*wb.z + v.w*wb.w;
        float p3 = v.x*wg.x + v.y*wg.y + v.z*wg.z + v.w*wg.w;
#pragma unroll
        for (int s = 1; s < 16; s <<= 1) {
            p1 += __shfl_xor(p1, s);
            p2 += __shfl_xor(p2, s);
            p3 += __shfl_xor(p3, s);
        }
        if (lane == 0) {
            pa[i] = p1;
            pb[i] = p2;
            hbuf[i] = p3;
        }
        return;
    }
    const int hb = bid - nodeBlocks;
    const int c = hb / Rh;
    const int r = hb - c * Rh;
    const int lo = r * RANGE_H;
    for (int j = tid; j < RANGE_H / 2; j += BD_H) t32[j] = 0u;
    __syncthreads();
    const int e_lo = c * CHh;
    const int e_hi = (E < e_lo + CHh) ? E : (e_lo + CHh);
    const int* __restrict__ col = ei + E;
    for (int e = e_lo + tid * 4; e < e_hi; e += BD_H * 4) {
        if (vec && e + 3 < e_hi) {
            int4 cc = *(const int4*)(col + e);
            unsigned u;
            u = (unsigned)(cc.x - lo); if (u < RANGE_H) atomicAdd(&t32[u >> 1], 1u << ((u & 1) << 4));
            u = (unsigned)(cc.y - lo); if (u < RANGE_H) atomicAdd(&t32[u >> 1], 1u << ((u & 1) << 4));
            u = (unsigned)(cc.z - lo); if (u < RANGE_H) atomicAdd(&t32[u >> 1], 1u << ((u & 1) << 4));
            u = (unsigned)(cc.w - lo); if (u < RANGE_H) atomicAdd(&t32[u >> 1], 1u << ((u & 1) << 4));
        } else {
            int ee = (e_hi < e + 4) ? e_hi : e + 4;
            for (int q = e; q < ee; ++q) {
                unsigned u = (unsigned)(col[q] - lo);
                if (u < RANGE_H) atomicAdd(&t32[u >> 1], 1u << ((u & 1) << 4));
            }
        }
    }
    __syncthreads();
    const size_t base = (size_t)c * N;
    for (int j = tid; j < RANGE_H; j += BD_H) {
        int node = lo + j;
        if (node < N)
            pd[base + node] = (u16t)(t32[j >> 1] >> ((j & 1) << 4));
    }
}

// k2: blocks [0,dinvBlocks) compute dinv & g from u16 deg-partial; rest sigmoid.
__global__ __launch_bounds__(256)
void k2_dinv_sig(const int* __restrict__ ei,
                 const float* __restrict__ pa, const float* __restrict__ pb,
                 const float* __restrict__ b_edge,
                 const u16t* __restrict__ pd,
                 float* __restrict__ hbuf,       // in: h, out: g = h*dinv
                 float* __restrict__ dv1,
                 float* __restrict__ om, float* __restrict__ os,
                 int N, int E, int Ch, int dinvBlocks, int vec) {
    const int bid = blockIdx.x, tid = threadIdx.x;
    if (bid < dinvBlocks) {
        int i = bid * 256 + tid;
        if (i >= N) return;
        unsigned d0 = 1u, d1 = 0u, d2 = 0u, d3 = 0u;   // self-loop in d0
        int c = 0;
        for (; c + 3 < Ch; c += 4) {
            d0 += pd[(size_t)(c + 0) * N + i];
            d1 += pd[(size_t)(c + 1) * N + i];
            d2 += pd[(size_t)(c + 2) * N + i];
            d3 += pd[(size_t)(c + 3) * N + i];
        }
        for (; c < Ch; ++c) d0 += pd[(size_t)c * N + i];
        float dv = rsqrtf((float)((d0 + d1) + (d2 + d3)));
        hbuf[i] *= dv;
        dv1[i] = dv;
        return;
    }
    int t = (bid - dinvBlocks) * 256 + tid;
    int e0 = t * 4;
    const float b = b_edge[0];
    if (vec && e0 + 3 < E) {
        int4 r = *(const int4*)(ei + e0);
        int4 c = *(const int4*)(ei + E + e0);
        float4 m;
        m.x = 1.f / (1.f + expf(-(pa[r.x] + pb[c.x] + b)));
        m.y = 1.f / (1.f + expf(-(pa[r.y] + pb[c.y] + b)));
        m.z = 1.f / (1.f + expf(-(pa[r.z] + pb[c.z] + b)));
        m.w = 1.f / (1.f + expf(-(pa[r.w] + pb[c.w] + b)));
        *(float4*)(om + e0) = m;
        *(float4*)(os + e0) = make_float4(1.f - m.x, 1.f - m.y, 1.f - m.z, 1.f - m.w);
    } else if (e0 < E) {
        int ee = (E < e0 + 4) ? E : e0 + 4;
        for (int e = e0; e < ee; ++e) {
            float a = 1.f / (1.f + expf(-(pa[ei[e]] + pb[ei[E + e]] + b)));
            om[e] = a; os[e] = 1.f - a;
        }
    }
}

// k3: partitioned f32 scatter (unchanged from r7).
__global__ __launch_bounds__(BD_H)
void k3_scat(const int* __restrict__ ei,
             const float* __restrict__ g1,
             float* __restrict__ partial,
             int N, int E, int Cs, int Rs, int CHs, int vec) {
    __shared__ float table[RANGE_S];
    const int tid = threadIdx.x;
    const int c = blockIdx.x / Rs;
    const int r = blockIdx.x - c * Rs;
    const int lo = r * RANGE_S;
    for (int j = tid; j < RANGE_S; j += BD_H) table[j] = 0.f;
    __syncthreads();
    const int e_lo = c * CHs;
    const int e_hi = (E < e_lo + CHs) ? E : (e_lo + CHs);
    const int* __restrict__ row = ei;
    const int* __restrict__ col = ei + E;
    for (int e = e_lo + tid * 4; e < e_hi; e += BD_H * 4) {
        if (vec && e + 3 < e_hi) {
            int4 cc = *(const int4*)(col + e);
            int4 rr = *(const int4*)(row + e);
            unsigned u;
            u = (unsigned)(cc.x - lo); if (u < RANGE_S) atomicAdd(&table[u], g1[rr.x]);
            u = (unsigned)(cc.y - lo); if (u < RANGE_S) atomicAdd(&table[u], g1[rr.y]);
            u = (unsigned)(cc.z - lo); if (u < RANGE_S) atomicAdd(&table[u], g1[rr.z]);
            u = (unsigned)(cc.w - lo); if (u < RANGE_S) atomicAdd(&table[u], g1[rr.w]);
        } else {
            int ee = (e_hi < e + 4) ? e_hi : e + 4;
            for (int q = e; q < ee; ++q) {
                unsigned u = (unsigned)(col[q] - lo);
                if (u < RANGE_S) atomicAdd(&table[u], g1[row[q]]);
            }
        }
    }
    __syncthreads();
    const size_t base = (size_t)c * N;
    for (int j = tid; j < RANGE_S; j += BD_H) {
        int node = lo + j;
        if (node < N) partial[base + node] = table[j];
    }
}

// k4: one block/graph; fused partial-reduce + two chained ragged softmaxes.
__global__ __launch_bounds__(128)
void k4_softmax(const float* __restrict__ hbuf,   // g
                const float* __restrict__ dv1,
                const float* __restrict__ partial,
                float* __restrict__ accfb,
                const int* __restrict__ split_n,
                float* __restrict__ out_m, float* __restrict__ out_s,
                int N, int Cs) {
    __shared__ float red[128];
    __shared__ int ired[128];
    __shared__ int sh_off;
    __shared__ float sv[SOFT_LDS_CAP];
    const int g = blockIdx.x;
    const int tid = threadIdx.x;
    const int BD = blockDim.x;

    int part = 0;
    for (int j = tid; j < g; j += BD) part += split_n[j];
    ired[tid] = part; __syncthreads();
    for (int s = 64; s > 0; s >>= 1) {
        if (tid < s) ired[tid] += ired[tid + s];
        __syncthreads();
    }
    if (tid == 0) sh_off = ired[0];
    __syncthreads();
    const int off = sh_off;
    const int cnt = split_n[g];
    const bool fits = (cnt <= SOFT_LDS_CAP);

    for (int j = tid; j < cnt; j += BD) {
        int node = off + j;
        float s0 = hbuf[node], s1 = 0.f, s2 = 0.f, s3 = 0.f;
        int c = 0;
        for (; c + 3 < Cs; c += 4) {
            s0 += partial[(size_t)(c + 0) * N + node];
            s1 += partial[(size_t)(c + 1) * N + node];
            s2 += partial[(size_t)(c + 2) * N + node];
            s3 += partial[(size_t)(c + 3) * N + node];
        }
        for (; c < Cs; ++c) s0 += partial[(size_t)c * N + node];
        float a = dv1[node] * ((s0 + s1) + (s2 + s3));
        if (fits) sv[j] = a; else accfb[node] = a;
    }
    __syncthreads();

    // softmax #1
    float mx = -INFINITY;
    for (int j = tid; j < cnt; j += BD) mx = fmaxf(mx, fits ? sv[j] : accfb[off + j]);
    red[tid] = mx; __syncthreads();
    for (int s = 64; s > 0; s >>= 1) {
        if (tid < s) red[tid] = fmaxf(red[tid], red[tid + s]);
        __syncthreads();
    }
    mx = red[0]; __syncthreads();
    float sum = 0.f;
    for (int j = tid; j < cnt; j += BD) sum += expf((fits ? sv[j] : accfb[off + j]) - mx);
    red[tid] = sum; __syncthreads();
    for (int s = 64; s > 0; s >>= 1) {
        if (tid < s) red[tid] += red[tid + s];
        __syncthreads();
    }
    const float inv1 = 1.0f / red[0]; __syncthreads();
    for (int j = tid; j < cnt; j += BD) {
        float mv = expf((fits ? sv[j] : accfb[off + j]) - mx) * inv1;
        out_m[off + j] = mv;
        if (fits) sv[j] = mv;
    }
    __syncthreads();

    // softmax #2 over (1 - m)
    float mx2 = -INFINITY;
    for (int j = tid; j < cnt; j += BD)
        mx2 = fmaxf(mx2, 1.0f - (fits ? sv[j] : out_m[off + j]));
    red[tid] = mx2; __syncthreads();
    for (int s = 64; s > 0; s >>= 1) {
        if (tid < s) red[tid] = fmaxf(red[tid], red[tid + s]);
        __syncthreads();
    }
    mx2 = red[0]; __syncthreads();
    float sum2 = 0.f;
    for (int j = tid; j < cnt; j += BD)
        sum2 += expf(1.0f - (fits ? sv[j] : out_m[off + j]) - mx2);
    red[tid] = sum2; __syncthreads();
    for (int s = 64; s > 0; s >>= 1) {
        if (tid < s) red[tid] += red[tid + s];
        __syncthreads();
    }
    const float inv2 = 1.0f / red[0]; __syncthreads();
    for (int j = tid; j < cnt; j += BD)
        out_s[off + j] = expf(1.0f - (fits ? sv[j] : out_m[off + j]) - mx2) * inv2;
}

extern "C" void kernel_launch(void* const* d_in, const int* in_sizes, int n_in,
                              void* d_out, int out_size, void* d_ws, size_t ws_size,
                              hipStream_t stream) {
    const float* x      = (const float*)d_in[0];
    const int*   ei     = (const int*)d_in[1];
    const int*   splitn = (const int*)d_in[2];
    const float* W_edge = (const float*)d_in[3];
    const float* b_edge = (const float*)d_in[4];
    const float* W_gcn  = (const float*)d_in[5];

    const int N = in_sizes[0] / 64;
    const int E = in_sizes[1] / 2;
    const int G = in_sizes[2];

    float* out = (float*)d_out;
    float* edge_m = out;
    float* edge_s = out + E;
    float* node_m = out + 2LL * E;
    float* node_s = out + 2LL * E + N;

    int Cs = 64;
    while (Cs > 2 && (size_t)(5 + Cs) * N * sizeof(float) > ws_size) Cs >>= 1;
    const int Ch = Cs;                       // u16 partial always fits (half of f32)
    const int Rs = (N + RANGE_S - 1) / RANGE_S;
    const int Rh = (N + RANGE_H - 1) / RANGE_H;
    const int CHs = (((E + Cs - 1) / Cs) + 3) & ~3;
    const int CHh = (((E + Ch - 1) / Ch) + 3) & ~3;
    const int vec = ((E & 3) == 0) ? 1 : 0;

    float* pa      = (float*)d_ws;
    float* pb      = pa + N;
    float* hbuf    = pb + N;
    float* dv1     = hbuf + N;
    float* accfb   = dv1 + N;
    float* partial = accfb + N;              // f32 scatter partial (Cs*N)
    u16t*  pd      = (u16t*)partial;         // aliased u16 deg partial (Ch*N)

    const int nodeBlocks = (int)(((long long)N * 16 + BD_H - 1) / BD_H);
    const int dinvBlocks = (N + 255) / 256;
    const int sigBlocks  = ((E + 3) / 4 + 255) / 256;

    k1_node_hist<<<nodeBlocks + Rh * Ch, BD_H, 0, stream>>>(
        x, W_edge, W_gcn, ei, pa, pb, hbuf, pd, N, E, Ch, Rh, CHh, nodeBlocks, vec);
    k2_dinv_sig<<<dinvBlocks + sigBlocks, 256, 0, stream>>>(
        ei, pa, pb, b_edge, pd, hbuf, dv1, edge_m, edge_s, N, E, Ch, dinvBlocks, vec);
    k3_scat<<<Rs * Cs, BD_H, 0, stream>>>(ei, hbuf, partial, N, E, Cs, Rs, CHs, vec);
    k4_softmax<<<G, 128, 0, stream>>>(hbuf, dv1, partial, accfb, splitn,
                                      node_m, node_s, N, Cs);
}